// Round 4
// baseline (421.121 us; speedup 1.0000x reference)
//
#include <hip/hip_runtime.h>
#include <stdint.h>

#define N_NODES 100000
#define CH 128
#define K_NEIGH 16
#define XS_STRIDE 68   // X tile stride: 64 + 4 pad (rows 16B-aligned)
#define PS 132         // pivot stride: 128 + 4 (node-major [n][o])

// Swizzled pivot index: key flips o bits 3..4 by (n>>3)&3. Properties:
//  * b32 scatter (fixed o, lane=n): bank = 4*(n&7) + key-toggles -> lanes
//    n, n+8, n+16, n+24 hit distinct banks; 2-way over 64 lanes = free.
//  * float4 along o (o%4==0): XOR touches bits 3..4 only -> quad contiguous.
#define PSWZ(n, o) ((n) * PS + ((o) ^ ((((n) >> 3) & 3) << 3)))

// ============================================================================
// Round 12: latency restructure (r3 evidence: both kernels ~146us at 5x their
// floors, VALUBusy 27%, HBM 39%, VGPR stuck at 64 -> compiler killed the W
// prefetch; GEMM keeps VMEM+LDS on the FMA critical path).
//  k_dual:   lane=node, wave=32 o-rows. W via wave-uniform SCALAR loads
//            (SMEM pipe, no vmcnt in loop), X via ds_read_b32. Computes BOTH
//            GEMMs per staging; Out stored direct coalesced; Yt via PSWZ pivot.
//  k_gather: 32-node tiles, 19KB LDS, <=64 VGPR target -> 8 blocks/CU for the
//            HBM-bound gather; RMW-adds into Out (idempotent across reruns).
// ============================================================================

__global__ __launch_bounds__(256, 4) void k_dual(
    const float* __restrict__ X,    // [C][N] f32
    const float* __restrict__ W1,   // [o][c] f32
    const float* __restrict__ B1,
    const float* __restrict__ W2,   // [o][c] f32
    const float* __restrict__ B2,
    float*       __restrict__ Yt,   // [N][C] f32 (workspace)
    float*       __restrict__ Out)  // [O][N] f32
{
    __shared__ __align__(16) float Xs[CH * XS_STRIDE];  // 34.8 KB; P aliases

    const int t  = threadIdx.x;
    const int n0 = blockIdx.x * 64;
    const int V  = (N_NODES - n0 < 64) ? (N_NODES - n0) : 64;

    // ---- stage X tile as float4 (proven r3) ----
    for (int it = 0; it < 8; ++it) {
        const int idx = t + it * 256;          // 0..2047
        const int nq = idx & 15, c = idx >> 4;
        float4 v = make_float4(0.f, 0.f, 0.f, 0.f);
        if (nq * 4 < V)
            v = *(const float4*)&X[(size_t)c * N_NODES + n0 + nq * 4];
        *(float4*)&Xs[c * XS_STRIDE + nq * 4] = v;
    }
    __syncthreads();

    // ---- dual GEMM: lane = node, wave w owns o in [w*32, w*32+32) ----
    const int lane = t & 63;
    const int w    = __builtin_amdgcn_readfirstlane(t >> 6);  // wave-uniform
    const int ob   = w * 32;
    const float* __restrict__ w1b = W1 + (size_t)ob * CH;
    const float* __restrict__ w2b = W2 + (size_t)ob * CH;

    float acc1[32], acc2[32];
#pragma unroll
    for (int oo = 0; oo < 32; ++oo) { acc1[oo] = 0.0f; acc2[oo] = 0.0f; }

    // c chunked by 8: body ~512+512 FMA, stays I-cache friendly; oo fully
    // unrolled (static acc indexing -- rule: no dynamic ext-vector indexing).
#pragma unroll 1
    for (int c0 = 0; c0 < CH; c0 += 8) {
        float xv[8];
#pragma unroll
        for (int k = 0; k < 8; ++k)
            xv[k] = Xs[(c0 + k) * XS_STRIDE + lane];   // 2-way bank = free
#pragma unroll
        for (int oo = 0; oo < 32; ++oo) {
            const float* r1 = w1b + oo * CH + c0;      // wave-uniform -> s_load
            const float* r2 = w2b + oo * CH + c0;
#pragma unroll
            for (int k = 0; k < 8; ++k) {
                acc1[oo] = fmaf(r1[k], xv[k], acc1[oo]);
                acc2[oo] = fmaf(r2[k], xv[k], acc2[oo]);
            }
        }
    }

    // ---- Out = W1@X + biases: direct coalesced stores (no pivot) ----
    if (lane < V) {
        float* op = Out + n0 + lane;
#pragma unroll
        for (int oo = 0; oo < 32; ++oo) {
            const int o = ob + oo;
            op[(size_t)o * N_NODES] = acc1[oo] + B1[o] + B2[o];
        }
    }

    // ---- Yt via PSWZ pivot (acc2 is [oo][lane=n]; Yt wants [n][c]) ----
    __syncthreads();          // all Xs reads done
    float* P = Xs;            // [64 n][PS]
#pragma unroll
    for (int oo = 0; oo < 32; ++oo)
        P[PSWZ(lane, ob + oo)] = acc2[oo];   // b32 scatter, 2-way = free
    __syncthreads();

    // Yt row stores: 2048 float4s; 32 lanes cover one 512B row -> coalesced.
    for (int it = 0; it < 8; ++it) {
        const int idx = t + it * 256;          // 0..2047
        const int n = idx >> 5, c4 = idx & 31; // node row, float4 col
        if (n < V) {
            const float4 v = *(const float4*)&P[PSWZ(n, c4 * 4)];
            *(float4*)&Yt[(size_t)(n0 + n) * CH + c4 * 4] = v;
        }
    }
}

// ---------------------------------------------------------------------------
// Kernel 2: Out += gather-mean(Yt). 32-node tiles (3125 blocks, no tail).
// LDS 18.9 KB; VGPR target <=64 -> 8 blocks/CU.
// ---------------------------------------------------------------------------
__global__ __launch_bounds__(256, 8) void k_gather(
    const int*   __restrict__ adj,  // [N][K] int32
    const float* __restrict__ Yt,   // [N][C] f32
    float*       __restrict__ Out)  // [O][N] f32
{
    __shared__ __align__(16) float P[32 * PS];        // 16.9 KB
    __shared__ __align__(16) int adjS[32 * K_NEIGH];  // 2 KB

    const int t  = threadIdx.x;
    const int n0 = blockIdx.x * 32;   // N_NODES % 32 == 0: V always 32

    // ---- stage adj: 512 ints = 128 int4 ----
    if (t < 128)
        *(int4*)&adjS[t * 4] = *(const int4*)&adj[(size_t)n0 * K_NEIGH + t * 4];
    __syncthreads();

    // ---- gather-mean: 32-lane group per node, lane owns 4 channels ----
    {
        const int l4 = (t & 31) * 4;
        const int g  = t >> 5;
        for (int itp = 0; itp < 4; ++itp) {
            const int n = itp * 8 + g;
            int js[K_NEIGH];
#pragma unroll
            for (int k = 0; k < K_NEIGH; ++k) js[k] = adjS[n * K_NEIGH + k];
            float4 a0 = make_float4(0.f, 0.f, 0.f, 0.f);
            float4 a1 = make_float4(0.f, 0.f, 0.f, 0.f);
#pragma unroll
            for (int k = 0; k < K_NEIGH; k += 2) {
                const float4 v0 = *(const float4*)&Yt[(size_t)js[k]     * CH + l4];
                const float4 v1 = *(const float4*)&Yt[(size_t)js[k + 1] * CH + l4];
                a0.x += v0.x; a0.y += v0.y; a0.z += v0.z; a0.w += v0.w;
                a1.x += v1.x; a1.y += v1.y; a1.z += v1.z; a1.w += v1.w;
            }
            float4 s;
            s.x = (a0.x + a1.x) * 0.0625f;
            s.y = (a0.y + a1.y) * 0.0625f;
            s.z = (a0.z + a1.z) * 0.0625f;
            s.w = (a0.w + a1.w) * 0.0625f;
            *(float4*)&P[PSWZ(n, l4)] = s;   // contiguous 128B/group
        }
    }
    __syncthreads();

    // ---- RMW epilogue: Out[o][n0..n0+32) += P; float4 along n ----
    for (int it = 0; it < 4; ++it) {
        const int idx = t + it * 256;          // 0..1023
        const int o = idx >> 3, nq = idx & 7;  // 8 float4-cols of 32 nodes
        float* op = Out + (size_t)o * N_NODES + n0 + nq * 4;
        float4 cur = *(const float4*)op;
        cur.x += P[PSWZ(nq * 4 + 0, o)];
        cur.y += P[PSWZ(nq * 4 + 1, o)];
        cur.z += P[PSWZ(nq * 4 + 2, o)];
        cur.w += P[PSWZ(nq * 4 + 3, o)];
        *(float4*)op = cur;
    }
}

// ---------------------------------------------------------------------------
// Legacy fused kernel (round-8 audited) -- fallback if workspace too small.
// ---------------------------------------------------------------------------
__global__ __launch_bounds__(256, 2) void k_fused_legacy(
    const float* __restrict__ X,
    const int*   __restrict__ adj,
    const float* __restrict__ W1,
    const float* __restrict__ B1,
    const float* __restrict__ W2,
    const float* __restrict__ B2,
    float*       __restrict__ Out)
{
    __shared__ __align__(16) float Xs[CH * XS_STRIDE];
    __shared__ __align__(16) float As[CH * XS_STRIDE];
    __shared__ int adjS[64 * K_NEIGH];

    const int t  = threadIdx.x;
    const int n0 = blockIdx.x * 64;
    const int V  = (N_NODES - n0 < 64) ? (N_NODES - n0) : 64;

    {
        const int base  = n0 * K_NEIGH;
        const int valid = V * K_NEIGH;
        for (int idx = t; idx < 64 * K_NEIGH; idx += 256)
            adjS[idx] = (idx < valid) ? adj[base + idx] : 0;
    }
    for (int it = 0; it < 32; ++it) {
        const int idx = t + it * 256;
        const int n = idx & 63, c = idx >> 6;
        Xs[c * XS_STRIDE + n] =
            (n < V) ? X[(size_t)c * N_NODES + n0 + n] : 0.0f;
    }
    __syncthreads();

    {
        const int n_l = t & 63, q = t >> 6;
        int js[K_NEIGH];
#pragma unroll
        for (int k = 0; k < K_NEIGH; ++k) js[k] = adjS[n_l * K_NEIGH + k];
        if (n_l < V) {
            for (int cc = 0; cc < 32; ++cc) {
                const int c = q * 32 + cc;
                const float* xc = X + (size_t)c * N_NODES;
                float s = 0.0f;
#pragma unroll
                for (int k = 0; k < K_NEIGH; ++k) s += xc[js[k]];
                As[c * XS_STRIDE + n_l] = s * 0.0625f;
            }
        } else {
            for (int cc = 0; cc < 32; ++cc)
                As[(q * 32 + cc) * XS_STRIDE + n_l] = 0.0f;
        }
    }
    __syncthreads();

    const int ng = t & 7, og = t >> 3;
    float acc[4][8];
#pragma unroll
    for (int i = 0; i < 4; ++i)
#pragma unroll
        for (int j = 0; j < 8; ++j) acc[i][j] = 0.0f;

    const float* w1p = W1 + (og * 4) * CH;
    const float* w2p = W2 + (og * 4) * CH;
    for (int c = 0; c < CH; ++c) {
        float xv[8], av[8], w1v[4], w2v[4];
        *(float4*)&xv[0] = *(const float4*)&Xs[c * XS_STRIDE + ng * 8];
        *(float4*)&xv[4] = *(const float4*)&Xs[c * XS_STRIDE + ng * 8 + 4];
        *(float4*)&av[0] = *(const float4*)&As[c * XS_STRIDE + ng * 8];
        *(float4*)&av[4] = *(const float4*)&As[c * XS_STRIDE + ng * 8 + 4];
#pragma unroll
        for (int i = 0; i < 4; ++i) {
            w1v[i] = w1p[i * CH + c];
            w2v[i] = w2p[i * CH + c];
        }
#pragma unroll
        for (int i = 0; i < 4; ++i)
#pragma unroll
            for (int j = 0; j < 8; ++j)
                acc[i][j] += w1v[i] * xv[j] + w2v[i] * av[j];
    }

    __syncthreads();
    float* Zt = Xs;
#pragma unroll
    for (int i = 0; i < 4; ++i) {
        *(float4*)&Zt[(og * 4 + i) * XS_STRIDE + ng * 8]     = *(float4*)&acc[i][0];
        *(float4*)&Zt[(og * 4 + i) * XS_STRIDE + ng * 8 + 4] = *(float4*)&acc[i][4];
    }
    __syncthreads();
    for (int it = 0; it < 32; ++it) {
        const int idx = t + it * 256;
        const int n = idx & 63, o = idx >> 6;
        if (n < V) {
            Out[(size_t)o * N_NODES + n0 + n] =
                Zt[o * XS_STRIDE + n] + B1[o] + B2[o];
        }
    }
}

extern "C" void kernel_launch(void* const* d_in, const int* in_sizes, int n_in,
                              void* d_out, int out_size, void* d_ws, size_t ws_size,
                              hipStream_t stream) {
    const float* X   = (const float*)d_in[0];
    const int*   adj = (const int*)d_in[1];
    const float* W1  = (const float*)d_in[2];
    const float* B1  = (const float*)d_in[3];
    const float* W2  = (const float*)d_in[4];
    const float* B2  = (const float*)d_in[5];
    float* Out = (float*)d_out;

    const size_t yt_bytes = (size_t)N_NODES * CH * sizeof(float);  // 51.2 MB

    if (ws_size >= yt_bytes) {
        float* Yt = (float*)d_ws;
        const int nb1 = (N_NODES + 63) / 64;   // 1563
        const int nb2 = N_NODES / 32;          // 3125, exact
        k_dual<<<nb1, 256, 0, stream>>>(X, W1, B1, W2, B2, Yt, Out);
        k_gather<<<nb2, 256, 0, stream>>>(adj, Yt, Out);
    } else {
        const int nblocks = (N_NODES + 63) / 64;
        k_fused_legacy<<<nblocks, 256, 0, stream>>>(X, adj, W1, B1, W2, B2, Out);
    }
}

// Round 5
// 350.305 us; speedup vs baseline: 1.2022x; 1.2022x over previous
//
#include <hip/hip_runtime.h>
#include <stdint.h>

#define N_NODES 100000
#define CH 128
#define K_NEIGH 16
#define XS_STRIDE 68   // X tile stride: 64 + 4 pad (rows 16B-aligned)
#define PS 132         // pivot stride: 128 + 4 (node-major [n][o])

// Swizzled pivot index: key = ((n>>3)&3)<<3 flips o bits 3..4 only, so any
// 4-aligned float4 (o = 4l..4l+3) stays contiguous. Gather RMW: n const per
// 32-lane group -> contiguous 128-dword block -> conflict-free. Epilogue
// (lane=n, o fixed): banks (4n + o^key(n))%32 -> <=4-way.
#define PSWZ(n, o) ((n) * PS + ((o) ^ ((((n) >> 3) & 3) << 3)))

// ============================================================================
// Round 13 = round-11 structure (best: 293us) + batched-W GEMM passes.
// r4 post-mortem: scalar-W / split-gather both regressed (VGPR 56 -> acc
// spills; s_load shares lgkmcnt with ds_read; gather lost GEMM overlap).
// r3 evidence: VGPR stuck at 64 == W loads have zero prefetch distance.
// Fix: c-loop as 8 passes of {16 batched W float4 loads -> 512 pure LDS+FMA}.
// The batch is structurally separated from its uses -> one amortized vmcnt
// wait per pass instead of one per 4 FMA-bundles. ~115 VGPR, still 4 blk/CU.
// ============================================================================

// ---------------------------------------------------------------------------
// Kernel 1: Yt[N][C] = (W2 @ X)^T   (biases added in k_main)
// ---------------------------------------------------------------------------
__global__ __launch_bounds__(256, 4) void k_w2x_t(
    const float* __restrict__ X,    // [C][N] f32
    const float* __restrict__ W2,   // [o][c] f32
    float*       __restrict__ Yt)   // [N][C] f32 (workspace)
{
    __shared__ __align__(16) float Xs[CH * XS_STRIDE];  // 34.8 KB

    const int t  = threadIdx.x;
    const int n0 = blockIdx.x * 64;
    const int V  = (N_NODES - n0 < 64) ? (N_NODES - n0) : 64;

    // stage X tile as float4 (proven r3)
    for (int it = 0; it < 8; ++it) {
        const int idx = t + it * 256;          // 0..2047
        const int nq = idx & 15, c = idx >> 4;
        float4 v = make_float4(0.f, 0.f, 0.f, 0.f);
        if (nq * 4 < V)
            v = *(const float4*)&X[(size_t)c * N_NODES + n0 + nq * 4];
        *(float4*)&Xs[c * XS_STRIDE + nq * 4] = v;
    }
    __syncthreads();

    const int ng = t & 7, og = t >> 3;
    float acc[4][8];
#pragma unroll
    for (int i = 0; i < 4; ++i)
#pragma unroll
        for (int j = 0; j < 8; ++j) acc[i][j] = 0.0f;

    const float* w2p = W2 + (og * 4) * CH;

    // 8 passes: batch-load W for 16 channels (16 float4 = 64 VGPR), then
    // 512 FMAs of pure LDS+FMA. All wq indices compile-time static.
#pragma unroll 1
    for (int q = 0; q < 8; ++q) {
        const int cq = q * 16;
        float4 wq[4][4];
#pragma unroll
        for (int i = 0; i < 4; ++i)
#pragma unroll
            for (int u = 0; u < 4; ++u)
                wq[i][u] = *(const float4*)&w2p[i * CH + cq + u * 4];
#pragma unroll
        for (int u = 0; u < 4; ++u) {
#pragma unroll
            for (int e = 0; e < 4; ++e) {
                const int c = cq + u * 4 + e;
                float xv[8];
                *(float4*)&xv[0] = *(const float4*)&Xs[c * XS_STRIDE + ng * 8];
                *(float4*)&xv[4] = *(const float4*)&Xs[c * XS_STRIDE + ng * 8 + 4];
#pragma unroll
                for (int i = 0; i < 4; ++i) {
                    const float w = ((const float*)&wq[i][u])[e];
#pragma unroll
                    for (int j = 0; j < 8; ++j)
                        acc[i][j] = fmaf(w, xv[j], acc[i][j]);
                }
            }
        }
    }

    // Transposed store: per instr 8 nodes x 128B contiguous segments.
#pragma unroll
    for (int j = 0; j < 8; ++j) {
        const int n = ng * 8 + j;
        if (n < V) {
            float4 v = make_float4(acc[0][j], acc[1][j], acc[2][j], acc[3][j]);
            *(float4*)&Yt[(size_t)(n0 + n) * CH + og * 4] = v;
        }
    }
}

// ---------------------------------------------------------------------------
// Kernel 2: Out = W1@X + gather-mean(Yt) + B1 + B2
// LDS: Xs 34.8KB (aliased by pivot P after GEMM) + adjS 4KB -> 4 blocks/CU.
// ---------------------------------------------------------------------------
__global__ __launch_bounds__(256, 4) void k_main(
    const float* __restrict__ X,    // [C][N] f32
    const int*   __restrict__ adj,  // [N][K] int32
    const float* __restrict__ W1,   // [o][c] f32
    const float* __restrict__ B1,
    const float* __restrict__ B2,
    const float* __restrict__ Yt,   // [N][C] f32
    float*       __restrict__ Out)  // [O][N] f32
{
    __shared__ __align__(16) float Xs[CH * XS_STRIDE];  // 8704 f >= 64*132=8448
    __shared__ __align__(16) int adjS[64 * K_NEIGH];    // 1024 ints

    const int t  = threadIdx.x;
    const int n0 = blockIdx.x * 64;
    const int V  = (N_NODES - n0 < 64) ? (N_NODES - n0) : 64;

    // ---- stage adj as int4 (1024 ints = 256 int4s, 1 per thread) ----
    {
        const int base  = n0 * K_NEIGH;   // int index, 4-aligned
        const int valid = V * K_NEIGH;    // V%32==0 -> valid%4==0
        int4 a = make_int4(0, 0, 0, 0);
        if (t * 4 < valid)
            a = *(const int4*)&adj[base + t * 4];
        *(int4*)&adjS[t * 4] = a;
    }
    // ---- stage X tile as float4 ----
    for (int it = 0; it < 8; ++it) {
        const int idx = t + it * 256;
        const int nq = idx & 15, c = idx >> 4;
        float4 v = make_float4(0.f, 0.f, 0.f, 0.f);
        if (nq * 4 < V)
            v = *(const float4*)&X[(size_t)c * N_NODES + n0 + nq * 4];
        *(float4*)&Xs[c * XS_STRIDE + nq * 4] = v;
    }
    __syncthreads();

    // ---- GEMM (W1), batched-W passes ----
    const int ng = t & 7, og = t >> 3;
    float acc[4][8];
#pragma unroll
    for (int i = 0; i < 4; ++i)
#pragma unroll
        for (int j = 0; j < 8; ++j) acc[i][j] = 0.0f;

    const float* w1p = W1 + (og * 4) * CH;
#pragma unroll 1
    for (int q = 0; q < 8; ++q) {
        const int cq = q * 16;
        float4 wq[4][4];
#pragma unroll
        for (int i = 0; i < 4; ++i)
#pragma unroll
            for (int u = 0; u < 4; ++u)
                wq[i][u] = *(const float4*)&w1p[i * CH + cq + u * 4];
#pragma unroll
        for (int u = 0; u < 4; ++u) {
#pragma unroll
            for (int e = 0; e < 4; ++e) {
                const int c = cq + u * 4 + e;
                float xv[8];
                *(float4*)&xv[0] = *(const float4*)&Xs[c * XS_STRIDE + ng * 8];
                *(float4*)&xv[4] = *(const float4*)&Xs[c * XS_STRIDE + ng * 8 + 4];
#pragma unroll
                for (int i = 0; i < 4; ++i) {
                    const float w = ((const float*)&wq[i][u])[e];
#pragma unroll
                    for (int j = 0; j < 8; ++j)
                        acc[i][j] = fmaf(w, xv[j], acc[i][j]);
                }
            }
        }
    }

    // ---- pivot acc into swizzled node-major P (aliases Xs) ----
    __syncthreads();          // all Xs reads done
    float* P = Xs;            // [64 n][PS], swizzled
#pragma unroll
    for (int j = 0; j < 8; ++j) {
        const int n = ng * 8 + j;
        float4 v = make_float4(acc[0][j], acc[1][j], acc[2][j], acc[3][j]);
        *(float4*)&P[PSWZ(n, og * 4)] = v;
    }
    __syncthreads();

    // ---- gather-mean from Yt, RMW into P; 2 nodes in flight ----
    // 32-lane group per node; lane l owns channels 4l..4l+3 (float4).
    {
        const int l4 = (t & 31) * 4;
        const int g  = t >> 5;
        for (int itp = 0; itp < 4; ++itp) {
            const int nA = itp * 16 + g;
            const int nB = nA + 8;
            int jA[K_NEIGH], jB[K_NEIGH];
#pragma unroll
            for (int k = 0; k < K_NEIGH; ++k) jA[k] = adjS[nA * K_NEIGH + k];
#pragma unroll
            for (int k = 0; k < K_NEIGH; ++k) jB[k] = adjS[nB * K_NEIGH + k];
            float4 aA0 = make_float4(0.f, 0.f, 0.f, 0.f);
            float4 aA1 = make_float4(0.f, 0.f, 0.f, 0.f);
            float4 aB0 = make_float4(0.f, 0.f, 0.f, 0.f);
            float4 aB1 = make_float4(0.f, 0.f, 0.f, 0.f);
#pragma unroll
            for (int k = 0; k < K_NEIGH; k += 2) {
                const float4 vA0 = *(const float4*)&Yt[(size_t)jA[k]     * CH + l4];
                const float4 vA1 = *(const float4*)&Yt[(size_t)jA[k + 1] * CH + l4];
                const float4 vB0 = *(const float4*)&Yt[(size_t)jB[k]     * CH + l4];
                const float4 vB1 = *(const float4*)&Yt[(size_t)jB[k + 1] * CH + l4];
                aA0.x += vA0.x; aA0.y += vA0.y; aA0.z += vA0.z; aA0.w += vA0.w;
                aA1.x += vA1.x; aA1.y += vA1.y; aA1.z += vA1.z; aA1.w += vA1.w;
                aB0.x += vB0.x; aB0.y += vB0.y; aB0.z += vB0.z; aB0.w += vB0.w;
                aB1.x += vB1.x; aB1.y += vB1.y; aB1.z += vB1.z; aB1.w += vB1.w;
            }
            float4 cA = *(const float4*)&P[PSWZ(nA, l4)];
            cA.x += (aA0.x + aA1.x) * 0.0625f;
            cA.y += (aA0.y + aA1.y) * 0.0625f;
            cA.z += (aA0.z + aA1.z) * 0.0625f;
            cA.w += (aA0.w + aA1.w) * 0.0625f;
            *(float4*)&P[PSWZ(nA, l4)] = cA;
            float4 cB = *(const float4*)&P[PSWZ(nB, l4)];
            cB.x += (aB0.x + aB1.x) * 0.0625f;
            cB.y += (aB0.y + aB1.y) * 0.0625f;
            cB.z += (aB0.z + aB1.z) * 0.0625f;
            cB.w += (aB0.w + aB1.w) * 0.0625f;
            *(float4*)&P[PSWZ(nB, l4)] = cB;
        }
    }
    __syncthreads();

    // ---- epilogue: float4-per-thread o-major stores (1KB/wave-instr) ----
    for (int it = 0; it < 8; ++it) {
        const int idx = t + it * 256;          // 0..2047
        const int nq = idx & 15, o = idx >> 4; // o: 0..127
        if (nq * 4 < V) {
            const float bb = B1[o] + B2[o];
            float4 v;
            v.x = P[PSWZ(nq * 4 + 0, o)] + bb;
            v.y = P[PSWZ(nq * 4 + 1, o)] + bb;
            v.z = P[PSWZ(nq * 4 + 2, o)] + bb;
            v.w = P[PSWZ(nq * 4 + 3, o)] + bb;
            *(float4*)&Out[(size_t)o * N_NODES + n0 + nq * 4] = v;
        }
    }
}

// ---------------------------------------------------------------------------
// Legacy fused kernel (round-8 audited) -- fallback if workspace too small.
// ---------------------------------------------------------------------------
__global__ __launch_bounds__(256, 2) void k_fused_legacy(
    const float* __restrict__ X,
    const int*   __restrict__ adj,
    const float* __restrict__ W1,
    const float* __restrict__ B1,
    const float* __restrict__ W2,
    const float* __restrict__ B2,
    float*       __restrict__ Out)
{
    __shared__ __align__(16) float Xs[CH * XS_STRIDE];
    __shared__ __align__(16) float As[CH * XS_STRIDE];
    __shared__ int adjS[64 * K_NEIGH];

    const int t  = threadIdx.x;
    const int n0 = blockIdx.x * 64;
    const int V  = (N_NODES - n0 < 64) ? (N_NODES - n0) : 64;

    {
        const int base  = n0 * K_NEIGH;
        const int valid = V * K_NEIGH;
        for (int idx = t; idx < 64 * K_NEIGH; idx += 256)
            adjS[idx] = (idx < valid) ? adj[base + idx] : 0;
    }
    for (int it = 0; it < 32; ++it) {
        const int idx = t + it * 256;
        const int n = idx & 63, c = idx >> 6;
        Xs[c * XS_STRIDE + n] =
            (n < V) ? X[(size_t)c * N_NODES + n0 + n] : 0.0f;
    }
    __syncthreads();

    {
        const int n_l = t & 63, q = t >> 6;
        int js[K_NEIGH];
#pragma unroll
        for (int k = 0; k < K_NEIGH; ++k) js[k] = adjS[n_l * K_NEIGH + k];
        if (n_l < V) {
            for (int cc = 0; cc < 32; ++cc) {
                const int c = q * 32 + cc;
                const float* xc = X + (size_t)c * N_NODES;
                float s = 0.0f;
#pragma unroll
                for (int k = 0; k < K_NEIGH; ++k) s += xc[js[k]];
                As[c * XS_STRIDE + n_l] = s * 0.0625f;
            }
        } else {
            for (int cc = 0; cc < 32; ++cc)
                As[(q * 32 + cc) * XS_STRIDE + n_l] = 0.0f;
        }
    }
    __syncthreads();

    const int ng = t & 7, og = t >> 3;
    float acc[4][8];
#pragma unroll
    for (int i = 0; i < 4; ++i)
#pragma unroll
        for (int j = 0; j < 8; ++j) acc[i][j] = 0.0f;

    const float* w1p = W1 + (og * 4) * CH;
    const float* w2p = W2 + (og * 4) * CH;
    for (int c = 0; c < CH; ++c) {
        float xv[8], av[8], w1v[4], w2v[4];
        *(float4*)&xv[0] = *(const float4*)&Xs[c * XS_STRIDE + ng * 8];
        *(float4*)&xv[4] = *(const float4*)&Xs[c * XS_STRIDE + ng * 8 + 4];
        *(float4*)&av[0] = *(const float4*)&As[c * XS_STRIDE + ng * 8];
        *(float4*)&av[4] = *(const float4*)&As[c * XS_STRIDE + ng * 8 + 4];
#pragma unroll
        for (int i = 0; i < 4; ++i) {
            w1v[i] = w1p[i * CH + c];
            w2v[i] = w2p[i * CH + c];
        }
#pragma unroll
        for (int i = 0; i < 4; ++i)
#pragma unroll
            for (int j = 0; j < 8; ++j)
                acc[i][j] += w1v[i] * xv[j] + w2v[i] * av[j];
    }

    __syncthreads();
    float* Zt = Xs;
#pragma unroll
    for (int i = 0; i < 4; ++i) {
        *(float4*)&Zt[(og * 4 + i) * XS_STRIDE + ng * 8]     = *(float4*)&acc[i][0];
        *(float4*)&Zt[(og * 4 + i) * XS_STRIDE + ng * 8 + 4] = *(float4*)&acc[i][4];
    }
    __syncthreads();
    for (int it = 0; it < 32; ++it) {
        const int idx = t + it * 256;
        const int n = idx & 63, o = idx >> 6;
        if (n < V) {
            Out[(size_t)o * N_NODES + n0 + n] =
                Zt[o * XS_STRIDE + n] + B1[o] + B2[o];
        }
    }
}

extern "C" void kernel_launch(void* const* d_in, const int* in_sizes, int n_in,
                              void* d_out, int out_size, void* d_ws, size_t ws_size,
                              hipStream_t stream) {
    const float* X   = (const float*)d_in[0];
    const int*   adj = (const int*)d_in[1];
    const float* W1  = (const float*)d_in[2];
    const float* B1  = (const float*)d_in[3];
    const float* W2  = (const float*)d_in[4];
    const float* B2  = (const float*)d_in[5];
    float* Out = (float*)d_out;

    const int nblocks = (N_NODES + 63) / 64;  // 1563
    const size_t yt_bytes = (size_t)N_NODES * CH * sizeof(float);  // 51.2 MB

    if (ws_size >= yt_bytes) {
        float* Yt = (float*)d_ws;
        k_w2x_t<<<nblocks, 256, 0, stream>>>(X, W2, Yt);
        k_main<<<nblocks, 256, 0, stream>>>(X, adj, W1, B1, B2, Yt, Out);
    } else {
        k_fused_legacy<<<nblocks, 256, 0, stream>>>(X, adj, W1, B1, W2, B2, Out);
    }
}

// Round 6
// 281.883 us; speedup vs baseline: 1.4940x; 1.2427x over previous
//
#include <hip/hip_runtime.h>
#include <stdint.h>

#define N_NODES 100000
#define CH 128
#define K_NEIGH 16
#define TN 32          // node tile: 100000/32 = 3125 exact, no tails
#define XT_STRIDE 36   // 32 + 4 pad, rows 16B-aligned (36*4=144)
#define XS_STRIDE 68   // legacy kernel only
#define PS 132         // pivot stride: 128 + 4 (node-major [n][o])

// Swizzled pivot index: key flips o bits 3..4 by (n>>3)&3; 4-aligned float4
// along o stays contiguous; scatter/epilogue conflicts <=4-way (audited r3).
#define PSWZ(n, o) ((n) * PS + ((o) ^ ((((n) >> 3) & 3) << 3)))

// ============================================================================
// Round 14. Evidence r3-r5: (a) k_main is gather-BYTES-bound (819MB demand,
// 400MB HBM); (b) k_w2x_t is latency-bound at 2.6 waves/SIMD; (c) three
// attempts at source-level W prefetch were all elided (VGPR pinned at 64).
// Changes:
//  * Yt stored as bf16 (RNE): gather demand 819->410 MB. Error ~1e-3 << 2^-7.
//  * 32-node tiles both kernels: LDS 18.4/20.5 KB -> 8 blocks/CU (2x waves),
//    no tail guards (3125*32 exact). 4o x 4n per thread keeps x-reuse at 4.
// ============================================================================

__device__ __forceinline__ uint32_t pack_bf16x2(float a, float b) {
    union { float f; uint32_t u; } ua, ub;
    ua.f = a; ub.f = b;
    const uint32_t ra = (ua.u + 0x7fffu + ((ua.u >> 16) & 1u)) >> 16;
    const uint32_t rb = (ub.u + 0x7fffu + ((ub.u >> 16) & 1u)) >> 16;
    return ra | (rb << 16);
}
__device__ __forceinline__ float bf16_lo(uint32_t u) {
    union { uint32_t u; float f; } c; c.u = u << 16; return c.f;
}
__device__ __forceinline__ float bf16_hi(uint32_t u) {
    union { uint32_t u; float f; } c; c.u = u & 0xffff0000u; return c.f;
}

// ---------------------------------------------------------------------------
// Kernel 1: Yt[N][CH] = bf16((W2 @ X)^T). 32-node tile, 8 blocks/CU.
// Thread owns o = (t>>3)*4+i (i<4), n = (t&7)*4+j (j<4).
// ---------------------------------------------------------------------------
__global__ __launch_bounds__(256, 8) void k_w2x_t(
    const float*  __restrict__ X,    // [C][N] f32
    const float*  __restrict__ W2,   // [o][c] f32
    uint16_t*     __restrict__ Yt)   // [N][CH] bf16 (workspace)
{
    __shared__ __align__(16) float Xs[CH * XT_STRIDE];  // 18432 B

    const int t  = threadIdx.x;
    const int n0 = blockIdx.x * TN;

    // stage X tile: 1024 float4, 4 per thread, no guards
    for (int it = 0; it < 4; ++it) {
        const int idx = t + it * 256;          // 0..1023
        const int nq = idx & 7, c = idx >> 3;  // 8 float4-cols, 128 rows
        *(float4*)&Xs[c * XT_STRIDE + nq * 4] =
            *(const float4*)&X[(size_t)c * N_NODES + n0 + nq * 4];
    }
    __syncthreads();

    const int ng = t & 7, og = t >> 3;   // og in [0,32)
    float acc[4][4];
#pragma unroll
    for (int i = 0; i < 4; ++i)
#pragma unroll
        for (int j = 0; j < 4; ++j) acc[i][j] = 0.0f;

    const float* wp = W2 + (size_t)(og * 4) * CH;
#pragma unroll 1
    for (int c0 = 0; c0 < CH; c0 += 4) {
        float4 wq[4];
#pragma unroll
        for (int i = 0; i < 4; ++i)
            wq[i] = *(const float4*)&wp[i * CH + c0];
#pragma unroll
        for (int e = 0; e < 4; ++e) {
            const float4 xv = *(const float4*)&Xs[(c0 + e) * XT_STRIDE + ng * 4];
#pragma unroll
            for (int i = 0; i < 4; ++i) {
                const float w = ((const float*)&wq[i])[e];
                acc[i][0] = fmaf(w, xv.x, acc[i][0]);
                acc[i][1] = fmaf(w, xv.y, acc[i][1]);
                acc[i][2] = fmaf(w, xv.z, acc[i][2]);
                acc[i][3] = fmaf(w, xv.w, acc[i][3]);
            }
        }
    }

    // bf16 transposed store: per j, wave covers 8 nodes x 64B contiguous.
#pragma unroll
    for (int j = 0; j < 4; ++j) {
        const int n = n0 + ng * 4 + j;
        uint2 v;
        v.x = pack_bf16x2(acc[0][j], acc[1][j]);
        v.y = pack_bf16x2(acc[2][j], acc[3][j]);
        *(uint2*)&Yt[(size_t)n * CH + og * 4] = v;
    }
}

// ---------------------------------------------------------------------------
// Kernel 2: Out = W1@X + mean_k bf16(Yt)[adj] + B1 + B2. 32-node tile,
// LDS = 18432 (Xs, aliased by pivot P) + 2048 (adjS) = 20480 -> 8 blocks/CU.
// ---------------------------------------------------------------------------
__global__ __launch_bounds__(256, 8) void k_main(
    const float*    __restrict__ X,    // [C][N] f32
    const int*      __restrict__ adj,  // [N][K] int32
    const float*    __restrict__ W1,   // [o][c] f32
    const float*    __restrict__ B1,
    const float*    __restrict__ B2,
    const uint16_t* __restrict__ Yt,   // [N][CH] bf16
    float*          __restrict__ Out)  // [O][N] f32
{
    __shared__ __align__(16) float Xs[CH * XT_STRIDE];  // 4608 f; P needs 4224
    __shared__ __align__(16) int adjS[TN * K_NEIGH];    // 512 ints

    const int t  = threadIdx.x;
    const int n0 = blockIdx.x * TN;

    // stage adj: 512 ints = 128 int4
    if (t < 128)
        *(int4*)&adjS[t * 4] = *(const int4*)&adj[(size_t)n0 * K_NEIGH + t * 4];
    // stage X tile
    for (int it = 0; it < 4; ++it) {
        const int idx = t + it * 256;
        const int nq = idx & 7, c = idx >> 3;
        *(float4*)&Xs[c * XT_STRIDE + nq * 4] =
            *(const float4*)&X[(size_t)c * N_NODES + n0 + nq * 4];
    }
    __syncthreads();

    // ---- GEMM (W1): thread owns 4o x 4n ----
    const int ng = t & 7, og = t >> 3;
    float acc[4][4];
#pragma unroll
    for (int i = 0; i < 4; ++i)
#pragma unroll
        for (int j = 0; j < 4; ++j) acc[i][j] = 0.0f;

    const float* wp = W1 + (size_t)(og * 4) * CH;
#pragma unroll 1
    for (int c0 = 0; c0 < CH; c0 += 4) {
        float4 wq[4];
#pragma unroll
        for (int i = 0; i < 4; ++i)
            wq[i] = *(const float4*)&wp[i * CH + c0];
#pragma unroll
        for (int e = 0; e < 4; ++e) {
            const float4 xv = *(const float4*)&Xs[(c0 + e) * XT_STRIDE + ng * 4];
#pragma unroll
            for (int i = 0; i < 4; ++i) {
                const float w = ((const float*)&wq[i])[e];
                acc[i][0] = fmaf(w, xv.x, acc[i][0]);
                acc[i][1] = fmaf(w, xv.y, acc[i][1]);
                acc[i][2] = fmaf(w, xv.z, acc[i][2]);
                acc[i][3] = fmaf(w, xv.w, acc[i][3]);
            }
        }
    }

    // ---- pivot acc into swizzled node-major P (aliases Xs) ----
    __syncthreads();          // all Xs reads done
    float* P = Xs;            // [32 n][PS] swizzled, 4224 f <= 4608 f
#pragma unroll
    for (int j = 0; j < 4; ++j) {
        const int n = ng * 4 + j;
        float4 v = make_float4(acc[0][j], acc[1][j], acc[2][j], acc[3][j]);
        *(float4*)&P[PSWZ(n, og * 4)] = v;
    }
    __syncthreads();

    // ---- gather-mean from bf16 Yt, RMW into P ----
    // 8 groups of 32 lanes; group g handles nodes {g, 8+g, 16+g, 24+g};
    // lane l owns channels 4l..4l+3 (uint2 = 8B; 32 lanes = one 256B row).
    {
        const int l4 = (t & 31) * 4;
        const int g  = t >> 5;
        for (int itp = 0; itp < 4; ++itp) {
            const int n = itp * 8 + g;
            int js[K_NEIGH];
#pragma unroll
            for (int k = 0; k < K_NEIGH; ++k) js[k] = adjS[n * K_NEIGH + k];
            float4 a0 = make_float4(0.f, 0.f, 0.f, 0.f);
            float4 a1 = make_float4(0.f, 0.f, 0.f, 0.f);
#pragma unroll
            for (int k = 0; k < K_NEIGH; k += 2) {
                const uint2 v0 = *(const uint2*)&Yt[(size_t)js[k]     * CH + l4];
                const uint2 v1 = *(const uint2*)&Yt[(size_t)js[k + 1] * CH + l4];
                a0.x += bf16_lo(v0.x); a0.y += bf16_hi(v0.x);
                a0.z += bf16_lo(v0.y); a0.w += bf16_hi(v0.y);
                a1.x += bf16_lo(v1.x); a1.y += bf16_hi(v1.x);
                a1.z += bf16_lo(v1.y); a1.w += bf16_hi(v1.y);
            }
            float4 cur = *(const float4*)&P[PSWZ(n, l4)];
            cur.x += (a0.x + a1.x) * 0.0625f;
            cur.y += (a0.y + a1.y) * 0.0625f;
            cur.z += (a0.z + a1.z) * 0.0625f;
            cur.w += (a0.w + a1.w) * 0.0625f;
            *(float4*)&P[PSWZ(n, l4)] = cur;
        }
    }
    __syncthreads();

    // ---- epilogue: 1024 float4 stores, 4 per thread, o-major coalesced ----
    for (int it = 0; it < 4; ++it) {
        const int idx = t + it * 256;          // 0..1023
        const int o = idx >> 3, nq = idx & 7;
        const float bb = B1[o] + B2[o];
        float4 v;
        v.x = P[PSWZ(nq * 4 + 0, o)] + bb;
        v.y = P[PSWZ(nq * 4 + 1, o)] + bb;
        v.z = P[PSWZ(nq * 4 + 2, o)] + bb;
        v.w = P[PSWZ(nq * 4 + 3, o)] + bb;
        *(float4*)&Out[(size_t)o * N_NODES + n0 + nq * 4] = v;
    }
}

// ---------------------------------------------------------------------------
// Legacy fused kernel (audited) -- fallback if workspace too small.
// ---------------------------------------------------------------------------
__global__ __launch_bounds__(256, 2) void k_fused_legacy(
    const float* __restrict__ X,
    const int*   __restrict__ adj,
    const float* __restrict__ W1,
    const float* __restrict__ B1,
    const float* __restrict__ W2,
    const float* __restrict__ B2,
    float*       __restrict__ Out)
{
    __shared__ __align__(16) float Xs[CH * XS_STRIDE];
    __shared__ __align__(16) float As[CH * XS_STRIDE];
    __shared__ int adjS[64 * K_NEIGH];

    const int t  = threadIdx.x;
    const int n0 = blockIdx.x * 64;
    const int V  = (N_NODES - n0 < 64) ? (N_NODES - n0) : 64;

    {
        const int base  = n0 * K_NEIGH;
        const int valid = V * K_NEIGH;
        for (int idx = t; idx < 64 * K_NEIGH; idx += 256)
            adjS[idx] = (idx < valid) ? adj[base + idx] : 0;
    }
    for (int it = 0; it < 32; ++it) {
        const int idx = t + it * 256;
        const int n = idx & 63, c = idx >> 6;
        Xs[c * XS_STRIDE + n] =
            (n < V) ? X[(size_t)c * N_NODES + n0 + n] : 0.0f;
    }
    __syncthreads();

    {
        const int n_l = t & 63, q = t >> 6;
        int js[K_NEIGH];
#pragma unroll
        for (int k = 0; k < K_NEIGH; ++k) js[k] = adjS[n_l * K_NEIGH + k];
        if (n_l < V) {
            for (int cc = 0; cc < 32; ++cc) {
                const int c = q * 32 + cc;
                const float* xc = X + (size_t)c * N_NODES;
                float s = 0.0f;
#pragma unroll
                for (int k = 0; k < K_NEIGH; ++k) s += xc[js[k]];
                As[c * XS_STRIDE + n_l] = s * 0.0625f;
            }
        } else {
            for (int cc = 0; cc < 32; ++cc)
                As[(q * 32 + cc) * XS_STRIDE + n_l] = 0.0f;
        }
    }
    __syncthreads();

    const int ng = t & 7, og = t >> 3;
    float acc[4][8];
#pragma unroll
    for (int i = 0; i < 4; ++i)
#pragma unroll
        for (int j = 0; j < 8; ++j) acc[i][j] = 0.0f;

    const float* w1p = W1 + (og * 4) * CH;
    const float* w2p = W2 + (og * 4) * CH;
    for (int c = 0; c < CH; ++c) {
        float xv[8], av[8], w1v[4], w2v[4];
        *(float4*)&xv[0] = *(const float4*)&Xs[c * XS_STRIDE + ng * 8];
        *(float4*)&xv[4] = *(const float4*)&Xs[c * XS_STRIDE + ng * 8 + 4];
        *(float4*)&av[0] = *(const float4*)&As[c * XS_STRIDE + ng * 8];
        *(float4*)&av[4] = *(const float4*)&As[c * XS_STRIDE + ng * 8 + 4];
#pragma unroll
        for (int i = 0; i < 4; ++i) {
            w1v[i] = w1p[i * CH + c];
            w2v[i] = w2p[i * CH + c];
        }
#pragma unroll
        for (int i = 0; i < 4; ++i)
#pragma unroll
            for (int j = 0; j < 8; ++j)
                acc[i][j] += w1v[i] * xv[j] + w2v[i] * av[j];
    }

    __syncthreads();
    float* Zt = Xs;
#pragma unroll
    for (int i = 0; i < 4; ++i) {
        *(float4*)&Zt[(og * 4 + i) * XS_STRIDE + ng * 8]     = *(float4*)&acc[i][0];
        *(float4*)&Zt[(og * 4 + i) * XS_STRIDE + ng * 8 + 4] = *(float4*)&acc[i][4];
    }
    __syncthreads();
    for (int it = 0; it < 32; ++it) {
        const int idx = t + it * 256;
        const int n = idx & 63, o = idx >> 6;
        if (n < V) {
            Out[(size_t)o * N_NODES + n0 + n] =
                Zt[o * XS_STRIDE + n] + B1[o] + B2[o];
        }
    }
}

extern "C" void kernel_launch(void* const* d_in, const int* in_sizes, int n_in,
                              void* d_out, int out_size, void* d_ws, size_t ws_size,
                              hipStream_t stream) {
    const float* X   = (const float*)d_in[0];
    const int*   adj = (const int*)d_in[1];
    const float* W1  = (const float*)d_in[2];
    const float* B1  = (const float*)d_in[3];
    const float* W2  = (const float*)d_in[4];
    const float* B2  = (const float*)d_in[5];
    float* Out = (float*)d_out;

    const size_t yt_bytes = (size_t)N_NODES * CH * sizeof(uint16_t);  // 25.6 MB

    if (ws_size >= yt_bytes) {
        uint16_t* Yt = (uint16_t*)d_ws;
        const int nb = N_NODES / TN;   // 3125, exact
        k_w2x_t<<<nb, 256, 0, stream>>>(X, W2, Yt);
        k_main<<<nb, 256, 0, stream>>>(X, adj, W1, B1, B2, Yt, Out);
    } else {
        const int nblocks = (N_NODES + 63) / 64;
        k_fused_legacy<<<nblocks, 256, 0, stream>>>(X, adj, W1, B1, W2, B2, Out);
    }
}

// Round 7
// 248.869 us; speedup vs baseline: 1.6921x; 1.1327x over previous
//
#include <hip/hip_runtime.h>
#include <stdint.h>

#define N_NODES 100000
#define CH 128
#define K_NEIGH 16
#define TN 32          // k_main node tile: 100000/32 = 3125 exact
#define XT_STRIDE 36   // k_main X tile stride
#define XS_STRIDE 68   // legacy kernel only
#define PS 132         // pivot stride (node-major [n][o])

#define PSWZ(n, o) ((n) * PS + ((o) ^ ((((n) >> 3) & 3) << 3)))

// ============================================================================
// Round 15. Evidence r2-r6: the f32-VALU GEMM kernel is pinned at ~150us
// across every scheduling/occupancy variant (VGPR 32-64: compiler always
// sinks W loads; W2=64KB thrashes 32KB L1; all waves stall correlated).
// Exit per r6 falsifier: MFMA for the W2@X GEMM.
//  * k_wcvt: W2 -> hi/lo bf16 pair (once, 16K elems).
//  * k_w2x_mfma: 64-node tile; A-frags (W2 hi/lo) loaded ONCE per block;
//    X staged transposed in LDS as swizzled bf16 hi/lo; 3-MFMA hi/lo split
//    => f32-grade precision (absmax stays at bf16-Yt level, passing).
//  * k_main / legacy unchanged (r6 audited, 132us).
// ============================================================================

typedef short bf8v __attribute__((ext_vector_type(8)));   // 8 bf16 = 4 VGPR
typedef float f32x4 __attribute__((ext_vector_type(4)));

__device__ __forceinline__ uint32_t pack_bf16x2(float a, float b) {
    union { float f; uint32_t u; } ua, ub;
    ua.f = a; ub.f = b;
    const uint32_t ra = (ua.u + 0x7fffu + ((ua.u >> 16) & 1u)) >> 16;
    const uint32_t rb = (ub.u + 0x7fffu + ((ub.u >> 16) & 1u)) >> 16;
    return ra | (rb << 16);
}
__device__ __forceinline__ uint16_t bf16_rne(float f) {
    union { float f; uint32_t u; } c; c.f = f;
    return (uint16_t)((c.u + 0x7fffu + ((c.u >> 16) & 1u)) >> 16);
}
__device__ __forceinline__ float bf16_tof(uint16_t h) {
    union { uint32_t u; float f; } c; c.u = ((uint32_t)h) << 16; return c.f;
}
__device__ __forceinline__ float bf16_lo(uint32_t u) {
    union { uint32_t u; float f; } c; c.u = u << 16; return c.f;
}
__device__ __forceinline__ float bf16_hi(uint32_t u) {
    union { uint32_t u; float f; } c; c.u = u & 0xffff0000u; return c.f;
}

// ---------------------------------------------------------------------------
// Pre-kernel: W2 -> (hi, lo) bf16 planes. 16384 elements.
// ---------------------------------------------------------------------------
__global__ void k_wcvt(const float* __restrict__ W,
                       uint16_t* __restrict__ Wh, uint16_t* __restrict__ Wl) {
    const int i = blockIdx.x * 256 + threadIdx.x;
    if (i < CH * CH) {
        const float f = W[i];
        const uint16_t h = bf16_rne(f);
        Wh[i] = h;
        Wl[i] = bf16_rne(f - bf16_tof(h));
    }
}

// ---------------------------------------------------------------------------
// Kernel 1: Yt[N][CH] = bf16((W2 @ X)^T) via MFMA 16x16x32 bf16, hi/lo split.
// 64-node tile, 4 waves; wave w owns o in [32w, 32w+32).
// LDS: X^T as swizzled bf16 hi/lo planes, [64 n][128 c], 16KB each.
//   byte(n,c) = n*256 + ((2c) ^ ((n&7)<<4))   (XOR spreads banks; 16B blocks
//   map to aligned 16B blocks, so b128 frag reads stay contiguous).
// Frag layouts (guide-verified, m89): A row=l&15, k=(l>>4)*8+e;
//   B col=l&15, k=(l>>4)*8+e; D col=l&15, row=(l>>4)*4+r.
// ---------------------------------------------------------------------------
__global__ __launch_bounds__(256, 2) void k_w2x_mfma(
    const float*    __restrict__ X,    // [C][N] f32
    const uint16_t* __restrict__ W2h,  // [o][c] bf16 hi
    const uint16_t* __restrict__ W2l,  // [o][c] bf16 lo
    uint16_t*       __restrict__ Yt)   // [N][CH] bf16
{
    __shared__ __align__(16) uint16_t XsH[64 * 128];  // 16 KB
    __shared__ __align__(16) uint16_t XsL[64 * 128];  // 16 KB

    const int t  = threadIdx.x;
    const int n0 = blockIdx.x * 64;
    const int V  = (N_NODES - n0 < 64) ? (N_NODES - n0) : 64;

    // ---- stage X: load f32 coalesced, split hi/lo, transposed swizzled ----
    for (int it = 0; it < 8; ++it) {
        const int idx = t + it * 256;          // 0..2047
        const int nq = idx & 15, c = idx >> 4; // 16 float4-cols, 128 c-rows
        float4 v = make_float4(0.f, 0.f, 0.f, 0.f);
        if (nq * 4 < V)
            v = *(const float4*)&X[(size_t)c * N_NODES + n0 + nq * 4];
        const float vv0 = v.x, vv1 = v.y, vv2 = v.z, vv3 = v.w;
#pragma unroll
        for (int s = 0; s < 4; ++s) {
            const float f = (s == 0) ? vv0 : (s == 1) ? vv1 : (s == 2) ? vv2 : vv3;
            const int n = nq * 4 + s;
            const uint16_t h = bf16_rne(f);
            const uint16_t lo = bf16_rne(f - bf16_tof(h));
            const int byi = (n << 8) + (((c * 2)) ^ ((n & 7) << 4));
            XsH[byi >> 1] = h;
            XsL[byi >> 1] = lo;
        }
    }

    // ---- A-frags: W2 hi/lo, loaded once (contiguous dwordx4 per frag) ----
    const int l = t & 63;
    const int w = t >> 6;                 // wave id 0..3
    bf8v ah[2][4], al[2][4];
    const int ar = l & 15;                // A row within 16-tile
    const int ac = (l >> 4) * 8;          // A k-offset
#pragma unroll
    for (int ot = 0; ot < 2; ++ot)
#pragma unroll
        for (int ks = 0; ks < 4; ++ks) {
            const size_t off = (size_t)(w * 32 + ot * 16 + ar) * CH + ks * 32 + ac;
            ah[ot][ks] = *(const bf8v*)&W2h[off];
            al[ot][ks] = *(const bf8v*)&W2l[off];
        }
    __syncthreads();

    // ---- MFMA: D[o][n], 2 o-tiles x 4 n-tiles, K=128 in 4 steps ----
    f32x4 d[2][4];
#pragma unroll
    for (int ot = 0; ot < 2; ++ot)
#pragma unroll
        for (int nt = 0; nt < 4; ++nt)
            d[ot][nt] = (f32x4){0.f, 0.f, 0.f, 0.f};

#pragma unroll
    for (int ks = 0; ks < 4; ++ks) {
#pragma unroll
        for (int nt = 0; nt < 4; ++nt) {
            const int n  = nt * 16 + (l & 15);
            const int byi = (n << 8) + ((ks * 64 + ((l >> 4) * 16)) ^ ((n & 7) << 4));
            const bf8v bh = *(const bf8v*)((const char*)XsH + byi);
            const bf8v bl = *(const bf8v*)((const char*)XsL + byi);
#pragma unroll
            for (int ot = 0; ot < 2; ++ot) {
                d[ot][nt] = __builtin_amdgcn_mfma_f32_16x16x32_bf16(
                    ah[ot][ks], bh, d[ot][nt], 0, 0, 0);
                d[ot][nt] = __builtin_amdgcn_mfma_f32_16x16x32_bf16(
                    al[ot][ks], bh, d[ot][nt], 0, 0, 0);
                d[ot][nt] = __builtin_amdgcn_mfma_f32_16x16x32_bf16(
                    ah[ot][ks], bl, d[ot][nt], 0, 0, 0);
            }
        }
    }

    // ---- store: lane holds o = base+(l>>4)*4+r (r=0..3), n = nt*16+(l&15);
    //      pack 4 consecutive o as 2x bf16x2 -> uint2 (8B). Per instr:
    //      16 n-rows x 32B contiguous (4 lane-groups) = 512B.
#pragma unroll
    for (int ot = 0; ot < 2; ++ot)
#pragma unroll
        for (int nt = 0; nt < 4; ++nt) {
            const int n = nt * 16 + (l & 15);
            if (n < V) {
                const int o4 = w * 32 + ot * 16 + (l >> 4) * 4;
                uint2 pv;
                pv.x = pack_bf16x2(d[ot][nt][0], d[ot][nt][1]);
                pv.y = pack_bf16x2(d[ot][nt][2], d[ot][nt][3]);
                *(uint2*)&Yt[(size_t)(n0 + n) * CH + o4] = pv;
            }
        }
}

// ---------------------------------------------------------------------------
// Kernel 2 (r6 audited, unchanged): Out = W1@X + mean_k bf16(Yt)[adj] + biases
// ---------------------------------------------------------------------------
__global__ __launch_bounds__(256, 8) void k_main(
    const float*    __restrict__ X,    // [C][N] f32
    const int*      __restrict__ adj,  // [N][K] int32
    const float*    __restrict__ W1,   // [o][c] f32
    const float*    __restrict__ B1,
    const float*    __restrict__ B2,
    const uint16_t* __restrict__ Yt,   // [N][CH] bf16
    float*          __restrict__ Out)  // [O][N] f32
{
    __shared__ __align__(16) float Xs[CH * XT_STRIDE];
    __shared__ __align__(16) int adjS[TN * K_NEIGH];

    const int t  = threadIdx.x;
    const int n0 = blockIdx.x * TN;

    if (t < 128)
        *(int4*)&adjS[t * 4] = *(const int4*)&adj[(size_t)n0 * K_NEIGH + t * 4];
    for (int it = 0; it < 4; ++it) {
        const int idx = t + it * 256;
        const int nq = idx & 7, c = idx >> 3;
        *(float4*)&Xs[c * XT_STRIDE + nq * 4] =
            *(const float4*)&X[(size_t)c * N_NODES + n0 + nq * 4];
    }
    __syncthreads();

    const int ng = t & 7, og = t >> 3;
    float acc[4][4];
#pragma unroll
    for (int i = 0; i < 4; ++i)
#pragma unroll
        for (int j = 0; j < 4; ++j) acc[i][j] = 0.0f;

    const float* wp = W1 + (size_t)(og * 4) * CH;
#pragma unroll 1
    for (int c0 = 0; c0 < CH; c0 += 4) {
        float4 wq[4];
#pragma unroll
        for (int i = 0; i < 4; ++i)
            wq[i] = *(const float4*)&wp[i * CH + c0];
#pragma unroll
        for (int e = 0; e < 4; ++e) {
            const float4 xv = *(const float4*)&Xs[(c0 + e) * XT_STRIDE + ng * 4];
#pragma unroll
            for (int i = 0; i < 4; ++i) {
                const float w = ((const float*)&wq[i])[e];
                acc[i][0] = fmaf(w, xv.x, acc[i][0]);
                acc[i][1] = fmaf(w, xv.y, acc[i][1]);
                acc[i][2] = fmaf(w, xv.z, acc[i][2]);
                acc[i][3] = fmaf(w, xv.w, acc[i][3]);
            }
        }
    }

    __syncthreads();
    float* P = Xs;
#pragma unroll
    for (int j = 0; j < 4; ++j) {
        const int n = ng * 4 + j;
        float4 v = make_float4(acc[0][j], acc[1][j], acc[2][j], acc[3][j]);
        *(float4*)&P[PSWZ(n, og * 4)] = v;
    }
    __syncthreads();

    {
        const int l4 = (t & 31) * 4;
        const int g  = t >> 5;
        for (int itp = 0; itp < 4; ++itp) {
            const int n = itp * 8 + g;
            int js[K_NEIGH];
#pragma unroll
            for (int k = 0; k < K_NEIGH; ++k) js[k] = adjS[n * K_NEIGH + k];
            float4 a0 = make_float4(0.f, 0.f, 0.f, 0.f);
            float4 a1 = make_float4(0.f, 0.f, 0.f, 0.f);
#pragma unroll
            for (int k = 0; k < K_NEIGH; k += 2) {
                const uint2 v0 = *(const uint2*)&Yt[(size_t)js[k]     * CH + l4];
                const uint2 v1 = *(const uint2*)&Yt[(size_t)js[k + 1] * CH + l4];
                a0.x += bf16_lo(v0.x); a0.y += bf16_hi(v0.x);
                a0.z += bf16_lo(v0.y); a0.w += bf16_hi(v0.y);
                a1.x += bf16_lo(v1.x); a1.y += bf16_hi(v1.x);
                a1.z += bf16_lo(v1.y); a1.w += bf16_hi(v1.y);
            }
            float4 cur = *(const float4*)&P[PSWZ(n, l4)];
            cur.x += (a0.x + a1.x) * 0.0625f;
            cur.y += (a0.y + a1.y) * 0.0625f;
            cur.z += (a0.z + a1.z) * 0.0625f;
            cur.w += (a0.w + a1.w) * 0.0625f;
            *(float4*)&P[PSWZ(n, l4)] = cur;
        }
    }
    __syncthreads();

    for (int it = 0; it < 4; ++it) {
        const int idx = t + it * 256;
        const int o = idx >> 3, nq = idx & 7;
        const float bb = B1[o] + B2[o];
        float4 v;
        v.x = P[PSWZ(nq * 4 + 0, o)] + bb;
        v.y = P[PSWZ(nq * 4 + 1, o)] + bb;
        v.z = P[PSWZ(nq * 4 + 2, o)] + bb;
        v.w = P[PSWZ(nq * 4 + 3, o)] + bb;
        *(float4*)&Out[(size_t)o * N_NODES + n0 + nq * 4] = v;
    }
}

// ---------------------------------------------------------------------------
// Legacy fused kernel (audited) -- fallback if workspace too small.
// ---------------------------------------------------------------------------
__global__ __launch_bounds__(256, 2) void k_fused_legacy(
    const float* __restrict__ X,
    const int*   __restrict__ adj,
    const float* __restrict__ W1,
    const float* __restrict__ B1,
    const float* __restrict__ W2,
    const float* __restrict__ B2,
    float*       __restrict__ Out)
{
    __shared__ __align__(16) float Xs[CH * XS_STRIDE];
    __shared__ __align__(16) float As[CH * XS_STRIDE];
    __shared__ int adjS[64 * K_NEIGH];

    const int t  = threadIdx.x;
    const int n0 = blockIdx.x * 64;
    const int V  = (N_NODES - n0 < 64) ? (N_NODES - n0) : 64;

    {
        const int base  = n0 * K_NEIGH;
        const int valid = V * K_NEIGH;
        for (int idx = t; idx < 64 * K_NEIGH; idx += 256)
            adjS[idx] = (idx < valid) ? adj[base + idx] : 0;
    }
    for (int it = 0; it < 32; ++it) {
        const int idx = t + it * 256;
        const int n = idx & 63, c = idx >> 6;
        Xs[c * XS_STRIDE + n] =
            (n < V) ? X[(size_t)c * N_NODES + n0 + n] : 0.0f;
    }
    __syncthreads();

    {
        const int n_l = t & 63, q = t >> 6;
        int js[K_NEIGH];
#pragma unroll
        for (int k = 0; k < K_NEIGH; ++k) js[k] = adjS[n_l * K_NEIGH + k];
        if (n_l < V) {
            for (int cc = 0; cc < 32; ++cc) {
                const int c = q * 32 + cc;
                const float* xc = X + (size_t)c * N_NODES;
                float s = 0.0f;
#pragma unroll
                for (int k = 0; k < K_NEIGH; ++k) s += xc[js[k]];
                As[c * XS_STRIDE + n_l] = s * 0.0625f;
            }
        } else {
            for (int cc = 0; cc < 32; ++cc)
                As[(q * 32 + cc) * XS_STRIDE + n_l] = 0.0f;
        }
    }
    __syncthreads();

    const int ng = t & 7, og = t >> 3;
    float acc[4][8];
#pragma unroll
    for (int i = 0; i < 4; ++i)
#pragma unroll
        for (int j = 0; j < 8; ++j) acc[i][j] = 0.0f;

    const float* w1p = W1 + (og * 4) * CH;
    const float* w2p = W2 + (og * 4) * CH;
    for (int c = 0; c < CH; ++c) {
        float xv[8], av[8], w1v[4], w2v[4];
        *(float4*)&xv[0] = *(const float4*)&Xs[c * XS_STRIDE + ng * 8];
        *(float4*)&xv[4] = *(const float4*)&Xs[c * XS_STRIDE + ng * 8 + 4];
        *(float4*)&av[0] = *(const float4*)&As[c * XS_STRIDE + ng * 8];
        *(float4*)&av[4] = *(const float4*)&As[c * XS_STRIDE + ng * 8 + 4];
#pragma unroll
        for (int i = 0; i < 4; ++i) {
            w1v[i] = w1p[i * CH + c];
            w2v[i] = w2p[i * CH + c];
        }
#pragma unroll
        for (int i = 0; i < 4; ++i)
#pragma unroll
            for (int j = 0; j < 8; ++j)
                acc[i][j] += w1v[i] * xv[j] + w2v[i] * av[j];
    }

    __syncthreads();
    float* Zt = Xs;
#pragma unroll
    for (int i = 0; i < 4; ++i) {
        *(float4*)&Zt[(og * 4 + i) * XS_STRIDE + ng * 8]     = *(float4*)&acc[i][0];
        *(float4*)&Zt[(og * 4 + i) * XS_STRIDE + ng * 8 + 4] = *(float4*)&acc[i][4];
    }
    __syncthreads();
    for (int it = 0; it < 32; ++it) {
        const int idx = t + it * 256;
        const int n = idx & 63, o = idx >> 6;
        if (n < V) {
            Out[(size_t)o * N_NODES + n0 + n] =
                Zt[o * XS_STRIDE + n] + B1[o] + B2[o];
        }
    }
}

extern "C" void kernel_launch(void* const* d_in, const int* in_sizes, int n_in,
                              void* d_out, int out_size, void* d_ws, size_t ws_size,
                              hipStream_t stream) {
    const float* X   = (const float*)d_in[0];
    const int*   adj = (const int*)d_in[1];
    const float* W1  = (const float*)d_in[2];
    const float* B1  = (const float*)d_in[3];
    const float* W2  = (const float*)d_in[4];
    const float* B2  = (const float*)d_in[5];
    float* Out = (float*)d_out;

    const size_t yt_bytes = (size_t)N_NODES * CH * sizeof(uint16_t);  // 25.6 MB
    const size_t w_bytes  = (size_t)CH * CH * sizeof(uint16_t);       // 32 KB
    const size_t need     = yt_bytes + 2 * w_bytes;

    if (ws_size >= need) {
        uint16_t* Yt  = (uint16_t*)d_ws;
        uint16_t* W2h = Yt + (size_t)N_NODES * CH;      // element offset
        uint16_t* W2l = W2h + (size_t)CH * CH;
        k_wcvt<<<(CH * CH + 255) / 256, 256, 0, stream>>>(W2, W2h, W2l);
        const int nb1 = (N_NODES + 63) / 64;   // 1563
        k_w2x_mfma<<<nb1, 256, 0, stream>>>(X, W2h, W2l, Yt);
        const int nb2 = N_NODES / TN;          // 3125
        k_main<<<nb2, 256, 0, stream>>>(X, adj, W1, B1, B2, Yt, Out);
    } else {
        const int nblocks = (N_NODES + 63) / 64;
        k_fused_legacy<<<nblocks, 256, 0, stream>>>(X, adj, W1, B1, W2, B2, Out);
    }
}